// Round 6
// baseline (389.391 us; speedup 1.0000x reference)
//
#include <hip/hip_runtime.h>
#include <stdint.h>

#define NROWS 32768
#define KP    4000
#define KPAD  4096
#define DIM   128
#define CL    1000
#define HREAL 125          // 125 halves x 32 proxies = 4000 exactly

typedef unsigned short u16;
typedef unsigned long long u64;
typedef unsigned short u16x8 __attribute__((ext_vector_type(8)));
typedef __bf16 bf16x8 __attribute__((ext_vector_type(8)));
typedef float f32x16 __attribute__((ext_vector_type(16)));
typedef float f32x4 __attribute__((ext_vector_type(4)));   // for nontemporal stores

// ---------- helpers ----------

// Map float to a 32-bit key with the same total order (handles negatives).
__device__ __forceinline__ unsigned int f2ord(float f) {
    unsigned int u = __float_as_uint(f);
    return (u & 0x80000000u) ? ~u : (u | 0x80000000u);
}

__device__ __forceinline__ u16 bf16rne(float f) {
    unsigned u = __float_as_uint(f);
    return (u16)((u + 0x7FFFu + ((u >> 16) & 1u)) >> 16);
}
__device__ __forceinline__ float bf2f(u16 h) {
    return __uint_as_float(((unsigned)h) << 16);
}
// 3-way bf16 split: v ~= h + m + l with |err| ~ 2^-27 |v|
__device__ __forceinline__ void split3(float v, u16& h, u16& m, u16& l) {
    h = bf16rne(v);
    float r1 = v - bf2f(h);
    m = bf16rne(r1);
    float r2 = r1 - bf2f(m);
    l = bf16rne(r2);
}

__device__ __forceinline__ f32x16 mfma16(bf16x8 a, bf16x8 b, f32x16 c) {
    return __builtin_amdgcn_mfma_f32_32x32x16_bf16(a, b, c, 0, 0, 0);
}

// async global->LDS 16B per lane; dest must be linear (base + lane*16).
__device__ __forceinline__ void g2lds16(const void* g, void* l) {
    __builtin_amdgcn_global_load_lds(
        (const __attribute__((address_space(1))) unsigned int*)(uintptr_t)g,
        (__attribute__((address_space(3))) unsigned int*)(uintptr_t)l,
        16, 0, 0);
}

// nontemporal 16B store wrapper (clang builtin needs ext-vector, not float4)
__device__ __forceinline__ void nt_store4(const float4& v, float4* dst) {
    __builtin_nontemporal_store(*(const f32x4*)&v, (f32x4*)dst);
}

// ---------- prep ----------
// psplit_sw layout (ushort): [half:128][s:3][row:32][chunkpos:16][e:8]
//   chunkpos = chunk ^ (row & 7)  -- pre-swizzled so argmin stages with
//   linear global_load_lds (rule #21). Also: packed init, p2pad.
__global__ void prep_kernel(const float* __restrict__ proxies,
                            u16* __restrict__ psplit_sw,
                            float* __restrict__ p2pad,
                            u64* __restrict__ packed) {
    int i = blockIdx.x * 256 + threadIdx.x;        // grid 384*256 = 98304
    if (i < NROWS) packed[i] = ~0ull;
    if (i < KPAD) {
        if (i < KP) {
            const float4* p = (const float4*)(proxies + (size_t)i * DIM);
            float s = 0.f;
            #pragma unroll
            for (int d = 0; d < DIM / 4; d++) {
                float4 v = p[d];
                s = fmaf(v.x, v.x, s);
                s = fmaf(v.y, v.y, s);
                s = fmaf(v.z, v.z, s);
                s = fmaf(v.w, v.w, s);
            }
            p2pad[i] = s;
        } else {
            p2pad[i] = __builtin_inff();           // padded proxies never win
        }
    }
    if (i >= 32768 && i < 98304) {                 // proxy splits: (k, 8-col chunk)
        int j = i - 32768;
        int k = j >> 4, c = j & 15;
        float vals[8];
        if (k < KP) {
            const float4* p = (const float4*)(proxies + (size_t)k * DIM + c * 8);
            float4 a = p[0], b = p[1];
            vals[0]=a.x; vals[1]=a.y; vals[2]=a.z; vals[3]=a.w;
            vals[4]=b.x; vals[5]=b.y; vals[6]=b.z; vals[7]=b.w;
        } else {
            #pragma unroll
            for (int e = 0; e < 8; e++) vals[e] = 0.f;
        }
        u16x8 vh, vm, vl;
        #pragma unroll
        for (int e = 0; e < 8; e++) {
            u16 h, m, l; split3(vals[e], h, m, l);
            vh[e] = h; vm[e] = m; vl[e] = l;
        }
        u16* dst = psplit_sw + (size_t)(k >> 5) * 12288 +
                   (size_t)(k & 31) * 128 + ((c ^ (k & 7)) << 3);
        *(u16x8*)(dst)        = vh;
        *(u16x8*)(dst + 4096) = vm;                // s stride = 32*128
        *(u16x8*)(dst + 8192) = vl;
    }
}

// ---------- argmin via bf16 6-term split GEMM on matrix cores ----------
// Round-4 skeleton (proven 62.6% MfmaUtil): 4 waves/block, 32 x-rows/wave,
// grid (256,3) = 3 blocks/CU, double-buffered 2x24KB LDS half-tiles staged
// with linear global_load_lds from the pre-swizzled image.
// Changes vs round 4 (kill the epilogue critical path):
//  - x fragments built IN-KERNEL from x, scaled by -2 (exact pow2 scale),
//    so MFMA accumulates -2*dot directly; no xfrag workspace.
//  - acc0 initialized with p2[k] (prefetched 1 half ahead into registers):
//    score = acc0[t] + acc1[t]; epilogue is add+min only, no loads, no fmaf.
// Tie-break preserved: strict <, packed u64 atomicMin.
__global__ void __launch_bounds__(256, 3)
argmin_mfma(const float* __restrict__ x,
            const u16* __restrict__ psplit_sw,
            const float* __restrict__ p2pad,
            u64* __restrict__ packed) {
    __shared__ __align__(16) u16 buf[2][12288];    // 2 x 24KB
    const int tid  = threadIdx.x;
    const int lane = tid & 63;
    const int w    = tid >> 6;
    const int g    = blockIdx.x * 4 + w;           // 32-row group
    const int r31  = lane & 31;
    const int hl   = lane >> 5;
    const int r7   = r31 & 7;

    // B fragments: splits of -2*x for this wave's 32 rows, all of D.
    // element (s,kk,e) for this lane = (-2x)_s[g*32+r31][kk*16 + hl*8 + e]
    bf16x8 xf[3][8];
    {
        const float* xrow = x + ((size_t)g * 32 + r31) * DIM + hl * 8;
        #pragma unroll
        for (int kk = 0; kk < 8; kk++) {
            float4 a = *(const float4*)(xrow + kk * 16);
            float4 b = *(const float4*)(xrow + kk * 16 + 4);
            float v[8] = {a.x, a.y, a.z, a.w, b.x, b.y, b.z, b.w};
            u16x8 vh, vm, vl;
            #pragma unroll
            for (int e = 0; e < 8; e++) {
                u16 hh, mm, ll; split3(-2.f * v[e], hh, mm, ll);
                vh[e] = hh; vm[e] = mm; vl[e] = ll;
            }
            xf[0][kk] = *(bf16x8*)&vh;
            xf[1][kk] = *(bf16x8*)&vm;
            xf[2][kk] = *(bf16x8*)&vl;
        }
    }

    // half-tile range: 43 / 43 / 39 (3 k-columns)
    int h0, h1;
    if      (blockIdx.y == 0) { h0 = 0;  h1 = 43; }
    else if (blockIdx.y == 1) { h0 = 43; h1 = 86; }
    else                      { h0 = 86; h1 = HREAL; }

    const int soff = w * 3072 + lane * 8;          // linear stage slice (u16)

    // prologue: stage h0; prefetch p2(h0) quads into qn
    float4 qn0, qn1, qn2, qn3;
    {
        const u16* src = psplit_sw + (size_t)h0 * 12288 + soff;
        u16* dst = &buf[h0 & 1][0] + soff;
        #pragma unroll
        for (int j = 0; j < 6; j++) g2lds16(src + j*512, dst + j*512);
        const float* q = p2pad + (h0 << 5) + (hl << 2);
        qn0 = *(const float4*)(q);
        qn1 = *(const float4*)(q + 8);
        qn2 = *(const float4*)(q + 16);
        qn3 = *(const float4*)(q + 24);
    }
    __syncthreads();

    float best = __builtin_inff();
    int bestk = 0;

    for (int h = h0; h < h1; ++h) {
        const int p = h & 1;
        // issue next half's stage first (flies under the MFMAs)
        if (h + 1 < h1) {
            const u16* src = psplit_sw + (size_t)(h + 1) * 12288 + soff;
            u16* dst = &buf[p ^ 1][0] + soff;
            #pragma unroll
            for (int j = 0; j < 6; j++) g2lds16(src + j*512, dst + j*512);
        }

        // acc0 init = p2 for this half (qn holds it); acc1 = 0.
        // acc element [j*4+e] <-> proxy row 4*hl + 8*j + e.
        f32x16 acc0, acc1;
        acc0[0]=qn0.x;  acc0[1]=qn0.y;  acc0[2]=qn0.z;  acc0[3]=qn0.w;
        acc0[4]=qn1.x;  acc0[5]=qn1.y;  acc0[6]=qn1.z;  acc0[7]=qn1.w;
        acc0[8]=qn2.x;  acc0[9]=qn2.y;  acc0[10]=qn2.z; acc0[11]=qn2.w;
        acc0[12]=qn3.x; acc0[13]=qn3.y; acc0[14]=qn3.z; acc0[15]=qn3.w;
        #pragma unroll
        for (int t = 0; t < 16; t++) acc1[t] = 0.f;

        // prefetch p2 for NEXT half (flies under the MFMAs)
        if (h + 1 < h1) {
            const float* q = p2pad + ((h + 1) << 5) + (hl << 2);
            qn0 = *(const float4*)(q);
            qn1 = *(const float4*)(q + 8);
            qn2 = *(const float4*)(q + 16);
            qn3 = *(const float4*)(q + 24);
        }

        const u16* B = &buf[p][0];
        __builtin_amdgcn_s_setprio(1);
        #pragma unroll
        for (int kk = 0; kk < 8; kk += 2) {
            int c0 = ((kk << 1) | hl) ^ r7;        // swizzled 16B chunk index
            int c1 = (((kk + 1) << 1) | hl) ^ r7;
            const u16* b0 = B + (r31 << 7) + (c0 << 3);
            const u16* b1 = B + (r31 << 7) + (c1 << 3);
            bf16x8 a0h = *(const bf16x8*)(b0);
            bf16x8 a0m = *(const bf16x8*)(b0 + 4096);
            bf16x8 a0l = *(const bf16x8*)(b0 + 8192);
            bf16x8 a1h = *(const bf16x8*)(b1);
            bf16x8 a1m = *(const bf16x8*)(b1 + 4096);
            bf16x8 a1l = *(const bf16x8*)(b1 + 8192);
            bf16x8 b0h = xf[0][kk],   b0m = xf[1][kk],   b0l = xf[2][kk];
            bf16x8 b1h = xf[0][kk+1], b1m = xf[1][kk+1], b1l = xf[2][kk+1];
            // 6 terms down to 2^-18: hh, hm, mh, hl, lh, mm
            acc0 = mfma16(a0h, b0h, acc0);  acc1 = mfma16(a1h, b1h, acc1);
            acc0 = mfma16(a0h, b0m, acc0);  acc1 = mfma16(a1h, b1m, acc1);
            acc0 = mfma16(a0m, b0h, acc0);  acc1 = mfma16(a1m, b1h, acc1);
            acc0 = mfma16(a0h, b0l, acc0);  acc1 = mfma16(a1h, b1l, acc1);
            acc0 = mfma16(a0l, b0h, acc0);  acc1 = mfma16(a1l, b1h, acc1);
            acc0 = mfma16(a0m, b0m, acc0);  acc1 = mfma16(a1m, b1m, acc1);
        }
        __builtin_amdgcn_s_setprio(0);

        // score = acc0 (has p2 baked in) + acc1; running argmin.
        // proxy index = kb + 4*hl + 8*j + e, element t = j*4+e.
        int kb = h << 5;
        #pragma unroll
        for (int j = 0; j < 4; j++) {
            #pragma unroll
            for (int e = 0; e < 4; e++) {
                float sc = acc0[j*4 + e] + acc1[j*4 + e];
                int ki = kb + (hl << 2) + (j << 3) + e;
                if (sc < best) { best = sc; bestk = ki; }  // strict <: first-min
            }
        }
        asm volatile("s_waitcnt vmcnt(0)" ::: "memory");   // next half staged
        __syncthreads();
    }

    u64 key = ((u64)f2ord(best) << 32) | (unsigned)bestk;
    u64 other = __shfl_xor(key, 32);
    key = other < key ? other : key;
    if (hl == 0) atomicMin(&packed[(size_t)g * 32 + r31], key);
}

// ---------- fused output kernel ----------
// blocks [0, 8192)       : labels gather  (4 rows/block, 1 wave/row)
// blocks [8192, 12288)   : x copy         (out[0 : N*D) = x)
// blocks [12288, 16384)  : proxy gather   (out[N*D : 2*N*D) = proxies[idx])
__global__ void write_out(const float4* __restrict__ x4,
                          const float4* __restrict__ prox4,
                          const float4* __restrict__ lab4,
                          const u64* __restrict__ packed,
                          float4* __restrict__ out4) {
    int b = blockIdx.x;
    int tid = threadIdx.x;
    if (b < 8192) {
        int rr = tid >> 6;
        int ln = tid & 63;
        int n = b * 4 + rr;
        int k = (int)(unsigned int)(packed[n] & 0xFFFFFFFFull);
        const float4* src = lab4 + (size_t)k * (CL / 4);
        float4* dst = out4 + 2097152 + (size_t)n * (CL / 4);
        for (int d = ln; d < CL / 4; d += 64)
            nt_store4(src[d], dst + d);
    } else if (b < 12288) {
        int i = (b - 8192) * 256 + tid;              // [0, 1048576)
        nt_store4(x4[i], out4 + i);
    } else {
        int i = (b - 12288) * 256 + tid;             // [0, 1048576)
        int n = i >> 5;                              // DIM/4 = 32
        int d = i & 31;
        int k = (int)(unsigned int)(packed[n] & 0xFFFFFFFFull);
        nt_store4(prox4[(size_t)k * 32 + d], out4 + 1048576 + i);
    }
}

extern "C" void kernel_launch(void* const* d_in, const int* in_sizes, int n_in,
                              void* d_out, int out_size, void* d_ws, size_t ws_size,
                              hipStream_t stream) {
    const float* x       = (const float*)d_in[0];
    const float* proxies = (const float*)d_in[1];
    const float* labels  = (const float*)d_in[2];
    float* out = (float*)d_out;

    // workspace map:
    //   [0, 256K)        packed u64[32768]
    //   [256K, 272K)     p2pad f32[4096]
    //   [512K, 3.5M)     psplit_sw u16 [128][3][32][128] (pre-swizzled)
    u64*   packed    = (u64*)d_ws;
    float* p2pad     = (float*)((char*)d_ws + 262144);
    u16*   psplit_sw = (u16*)((char*)d_ws + 524288);

    prep_kernel<<<384, 256, 0, stream>>>(proxies, psplit_sw, p2pad, packed);

    argmin_mfma<<<dim3(256, 3), 256, 0, stream>>>(x, psplit_sw, p2pad, packed);

    write_out<<<16384, 256, 0, stream>>>(
        (const float4*)x, (const float4*)proxies, (const float4*)labels,
        packed, (float4*)out);
}